// Round 3
// baseline (506.933 us; speedup 1.0000x reference)
//
#include <hip/hip_runtime.h>

// QuantizedLinear: out[M,N] = (x[M,K] @ W^T) * scale + bias, W[N,K] = q - zp
// M = 8192, N = 4096, K = 4096.
// GEMM: 256x256 tile, BK=64, 8 waves (2x4). K-split 4-phase schedule:
// phases = (K-half x qm), full one-phase-ahead operand prefetch via ping-pong
// register banks (afA/afB/bfA/bfB, 64 regs total), 2 barriers + 1 counted
// vmcnt(4) per K-tile, conflict-free LDS swizzle via pre-swizzled global
// source, setprio around MFMA clusters, XCD block swizzle.

typedef __bf16 bf16x8 __attribute__((ext_vector_type(8)));
typedef float  f32x4  __attribute__((ext_vector_type(4)));

// ---------------- conversion kernels (unchanged) ----------------

__global__ __launch_bounds__(256) void cvt_x_bf16(
    const float4* __restrict__ x, uint4* __restrict__ o, int n8) {
  int i = blockIdx.x * 256 + threadIdx.x;
  if (i >= n8) return;
  float4 a = x[2 * i];
  float4 b = x[2 * i + 1];
  union { __bf16 h[8]; uint4 u; } r;
  r.h[0] = (__bf16)a.x; r.h[1] = (__bf16)a.y;
  r.h[2] = (__bf16)a.z; r.h[3] = (__bf16)a.w;
  r.h[4] = (__bf16)b.x; r.h[5] = (__bf16)b.y;
  r.h[6] = (__bf16)b.z; r.h[7] = (__bf16)b.w;
  o[i] = r.u;
}

__global__ __launch_bounds__(256) void cvt_w_bf16(
    const int4* __restrict__ q, const int* __restrict__ zp,
    uint4* __restrict__ o, int n8) {
  int i = blockIdx.x * 256 + threadIdx.x;
  if (i >= n8) return;
  int z = zp[0];
  int4 a = q[2 * i];
  int4 b = q[2 * i + 1];
  union { __bf16 h[8]; uint4 u; } r;
  r.h[0] = (__bf16)(float)(a.x - z); r.h[1] = (__bf16)(float)(a.y - z);
  r.h[2] = (__bf16)(float)(a.z - z); r.h[3] = (__bf16)(float)(a.w - z);
  r.h[4] = (__bf16)(float)(b.x - z); r.h[5] = (__bf16)(float)(b.y - z);
  r.h[6] = (__bf16)(float)(b.z - z); r.h[7] = (__bf16)(float)(b.w - z);
  o[i] = r.u;
}

// ---------------- 256^2 GEMM, K-split 4-phase schedule ----------------
// LDS half-slot (128 rows x 64 bf16 = 16KB), 16x32-subtiled + XOR swizzle.
// Phase map per tile t (d = t&1, e = d^1):
//   p1: MFMA(kh0,qm0) on afA,bfA      | read afB <- Ab(t) kh0
//   p2: MFMA(kh0,qm1) on afB,bfA      | read afA <- At(t) kh1, bfB <- B(t) kh1
//   -- barrier (guards p3 stages vs p2 reads)
//   p3: MFMA(kh1,qm0) on afA,bfB      | read afB <- Ab(t) kh1 | STAGE At,Bt(t+2)
//   -- vmcnt(4) + barrier (retires tile t+1 At/Bt/Bb; guards p4 stage vs p3 read)
//   p4: MFMA(kh1,qm1) on afB,bfB      | read afA <- At(t+1) kh0, bfA <- B(t+1) kh0
//                                     | STAGE Ab,Bb(t+2)
// Every MFMA cluster's operands were read >=1 phase earlier.

#define SLOT_A(d, h) ((((d) * 2 + (h)) << 14))
#define SLOT_B(d, h) ((1 << 16) + (((d) * 2 + (h)) << 14))

#define STAGE(gbase, ldsOff, h, s)                                            \
  do {                                                                        \
    const char* g_ = (gbase) + (size_t)(h) * 128 * K2 + (size_t)(s) * 128;    \
    __builtin_amdgcn_global_load_lds(                                         \
        (const __attribute__((address_space(1))) void*)(g_),                  \
        (__attribute__((address_space(3))) void*)(smem + (ldsOff) + wave * 2048), \
        16, 0, 0);                                                            \
    __builtin_amdgcn_global_load_lds(                                         \
        (const __attribute__((address_space(1))) void*)(g_ + 64),             \
        (__attribute__((address_space(3))) void*)(smem + (ldsOff) + wave * 2048 + 1024), \
        16, 0, 0);                                                            \
  } while (0)

#define LOAD_A(bank, d, qm, kh)                                               \
  do {                                                                        \
    _Pragma("unroll") for (int mf = 0; mf < 4; ++mf)                          \
        bank[mf] = *(const bf16x8*)(smem + SLOT_A(d, qm) +                    \
            (((wr * 4 + mf) * 2 + (kh)) << 10) + innerOff);                   \
  } while (0)

#define LOAD_B(bank, d, kh)                                                   \
  do {                                                                        \
    _Pragma("unroll") for (int j = 0; j < 4; ++j)                             \
        bank[j] = *(const bf16x8*)(smem + SLOT_B(d, (j >> 1)) +               \
            (((wc * 2 + (j & 1)) * 2 + (kh)) << 10) + innerOff);              \
  } while (0)

#define MFMA_PH(qm, AF, BF)                                                   \
  do {                                                                        \
    __builtin_amdgcn_s_setprio(1);                                            \
    _Pragma("unroll") for (int mf = 0; mf < 4; ++mf)                          \
    _Pragma("unroll") for (int j = 0; j < 4; ++j)                             \
        acc[qm][j >> 1][mf][j & 1] = __builtin_amdgcn_mfma_f32_16x16x32_bf16( \
            AF[mf], BF[j], acc[qm][j >> 1][mf][j & 1], 0, 0, 0);              \
    __builtin_amdgcn_s_setprio(0);                                            \
  } while (0)

// FULL: t+2 < nt (do stages, vmcnt(4)); PRE: t+1 < nt (p4 prefetch reads;
// if !FULL, drain with vmcnt(0) so the tail runs with everything resident).
#define TILE_K(t, d, e, FULL, PRE)                                            \
  do {                                                                        \
    /* p1 */                                                                  \
    LOAD_A(afB, d, 1, 0);                                                     \
    MFMA_PH(0, afA, bfA);                                                     \
    /* p2 */                                                                  \
    LOAD_A(afA, d, 0, 1);                                                     \
    LOAD_B(bfB, d, 1);                                                        \
    MFMA_PH(1, afB, bfA);                                                     \
    __builtin_amdgcn_s_barrier();                                             \
    /* p3 */                                                                  \
    LOAD_A(afB, d, 1, 1);                                                     \
    if (FULL) { STAGE(Abase, SLOT_A(d, 0), 0, (t) + 2);                       \
                STAGE(Bbase, SLOT_B(d, 0), 0, (t) + 2); }                     \
    MFMA_PH(0, afA, bfB);                                                     \
    if (FULL)     { asm volatile("s_waitcnt vmcnt(4)"); }                     \
    else if (PRE) { asm volatile("s_waitcnt vmcnt(0)"); }                     \
    __builtin_amdgcn_s_barrier();                                             \
    /* p4 */                                                                  \
    if (PRE) { LOAD_A(afA, e, 0, 0); LOAD_B(bfA, e, 0); }                     \
    if (FULL) { STAGE(Abase, SLOT_A(d, 1), 1, (t) + 2);                       \
                STAGE(Bbase, SLOT_B(d, 1), 1, (t) + 2); }                     \
    MFMA_PH(1, afB, bfB);                                                     \
  } while (0)

__global__ __launch_bounds__(512, 2) void gemm256(
    const __bf16* __restrict__ A, const __bf16* __restrict__ Bw,
    const float* __restrict__ scale, const float* __restrict__ bias,
    float* __restrict__ C) {
  extern __shared__ char smem[];

  constexpr int N = 4096, K = 4096;
  constexpr size_t K2 = (size_t)K * 2;  // row stride in bytes

  const int tid  = threadIdx.x;
  const int wave = tid >> 6;
  const int lane = tid & 63;
  const int fr   = lane & 15;   // fragment row (A) / col (B,C)
  const int quad = lane >> 4;   // 0..3
  const int wr   = wave >> 2;   // 0..1 (M within quadrant)
  const int wc   = wave & 3;    // 0..3 (N within quadrant)

  // T1: XCD swizzle, nwg = 512 (divisible by 8).
  const int nwg = gridDim.x;
  const int cpx = nwg >> 3;
  const int swzid = ((int)blockIdx.x & 7) * cpx + ((int)blockIdx.x >> 3);
  const int nbx = N >> 8;          // 16
  const int bx = swzid % nbx;
  const int by = swzid / nbx;

  // staging per-lane source: row = wave*16 + lane>>2 within half,
  // col-byte = ((lane&3)<<4) ^ (((lane>>3)&3)<<4)  (inverse swizzle)
  const int rowLane = wave * 16 + (lane >> 2);
  const int colLane = ((lane & 3) << 4) ^ (((lane >> 3) & 3) << 4);
  const char* Abase = (const char*)A  + (size_t)(by * 256 + rowLane) * K2 + colLane;
  const char* Bbase = (const char*)Bw + (size_t)(bx * 256 + rowLane) * K2 + colLane;

  // ds_read per-lane inner offset (within 1KB subtile), swizzled:
  const int innerOff = (fr << 6) | ((quad << 4) ^ (((fr >> 1) & 3) << 4));

  f32x4 acc[2][2][4][2] = {};
  bf16x8 afA[4], afB[4], bfA[4], bfB[4];

  const int nt = K >> 6;  // 64 K-tiles
  (void)nt;

  // prologue: stage tiles 0 and 1 fully (order matters for vmcnt ledger).
  STAGE(Abase, SLOT_A(0, 0), 0, 0);  // At(0)
  STAGE(Bbase, SLOT_B(0, 0), 0, 0);  // Bt(0)
  STAGE(Abase, SLOT_A(0, 1), 1, 0);  // Ab(0)
  STAGE(Bbase, SLOT_B(0, 1), 1, 0);  // Bb(0)
  STAGE(Abase, SLOT_A(1, 0), 0, 1);  // At(1)
  STAGE(Bbase, SLOT_B(1, 0), 0, 1);  // Bt(1)
  STAGE(Abase, SLOT_A(1, 1), 1, 1);  // Ab(1)
  STAGE(Bbase, SLOT_B(1, 1), 1, 1);  // Bb(1)
  asm volatile("s_waitcnt vmcnt(8)");   // tile 0 (oldest 8 loads) complete
  __builtin_amdgcn_s_barrier();
  LOAD_A(afA, 0, 0, 0);   // At(0) kh0
  LOAD_B(bfA, 0, 0);      // B(0) kh0

  for (int tt = 0; tt < 62; tt += 2) {
    TILE_K(tt,     0, 1, 1, 1);
    TILE_K(tt + 1, 1, 0, 1, 1);
  }
  TILE_K(62, 0, 1, 0, 1);   // drains vmcnt(0) at p3
  TILE_K(63, 1, 0, 0, 0);

  // epilogue: C/D layout col = lane&15, row = quad*4 + reg (m89-verified)
  const float s = scale[0];
#pragma unroll
  for (int qm = 0; qm < 2; ++qm)
#pragma unroll
    for (int mf = 0; mf < 4; ++mf) {
      const int row0 = by * 256 + qm * 128 + wr * 64 + mf * 16 + quad * 4;
#pragma unroll
      for (int qn = 0; qn < 2; ++qn)
#pragma unroll
        for (int nf = 0; nf < 2; ++nf) {
          const int col = bx * 256 + qn * 128 + wc * 32 + nf * 16 + fr;
          const float bv = bias[col];
          float* cp = C + (size_t)row0 * N + col;
#pragma unroll
          for (int r = 0; r < 4; ++r)
            cp[(size_t)r * N] = s * acc[qm][qn][mf][nf][r] + bv;
        }
    }
}

// ---------------- launch ----------------

extern "C" void kernel_launch(void* const* d_in, const int* in_sizes, int n_in,
                              void* d_out, int out_size, void* d_ws, size_t ws_size,
                              hipStream_t stream) {
  const int M = 8192, N = 4096, K = 4096;

  const float* x    = (const float*)d_in[0];
  const int*   qw   = (const int*)d_in[1];
  const int*   zp   = (const int*)d_in[2];
  const float* sc   = (const float*)d_in[3];
  const float* bias = (const float*)d_in[4];
  float* out = (float*)d_out;

  __bf16* x_bf = (__bf16*)d_ws;
  __bf16* w_bf = (__bf16*)((char*)d_ws + (size_t)M * K * sizeof(__bf16));

  {
    int n8 = (M * K) / 8;
    cvt_x_bf16<<<n8 / 256, 256, 0, stream>>>((const float4*)x, (uint4*)x_bf, n8);
  }
  {
    int n8 = (N * K) / 8;
    cvt_w_bf16<<<n8 / 256, 256, 0, stream>>>((const int4*)qw, zp, (uint4*)w_bf, n8);
  }

  static bool attr_set = false;
  if (!attr_set) {
    hipFuncSetAttribute((const void*)gemm256,
                        hipFuncAttributeMaxDynamicSharedMemorySize, 131072);
    attr_set = true;
  }
  gemm256<<<dim3(512), dim3(512), 131072, stream>>>(x_bf, w_bf, sc, bias, out);
}

// Round 4
// 480.928 us; speedup vs baseline: 1.0541x; 1.0541x over previous
//
#include <hip/hip_runtime.h>

// QuantizedLinear: out[M,N] = (x[M,K] @ W^T) * scale + bias, W[N,K] = q - zp
// M = 8192, N = 4096, K = 4096.
// GEMM: 256x256 tile, BK=64, 8 waves (2x4). TWO-phase/K-tile schedule
// (merged from R2's proven 4-phase): same-phase ds_reads + MFMA (compiler
// incremental lgkmcnt), stage-after-last-read, 2 barriers + 2x counted
// vmcnt(8) per tile, conflict-free LDS swizzle via pre-swizzled global
// source, setprio around MFMA clusters, XCD block swizzle.

typedef __bf16 bf16x8 __attribute__((ext_vector_type(8)));
typedef float  f32x4  __attribute__((ext_vector_type(4)));

// ---------------- conversion kernels (unchanged) ----------------

__global__ __launch_bounds__(256) void cvt_x_bf16(
    const float4* __restrict__ x, uint4* __restrict__ o, int n8) {
  int i = blockIdx.x * 256 + threadIdx.x;
  if (i >= n8) return;
  float4 a = x[2 * i];
  float4 b = x[2 * i + 1];
  union { __bf16 h[8]; uint4 u; } r;
  r.h[0] = (__bf16)a.x; r.h[1] = (__bf16)a.y;
  r.h[2] = (__bf16)a.z; r.h[3] = (__bf16)a.w;
  r.h[4] = (__bf16)b.x; r.h[5] = (__bf16)b.y;
  r.h[6] = (__bf16)b.z; r.h[7] = (__bf16)b.w;
  o[i] = r.u;
}

__global__ __launch_bounds__(256) void cvt_w_bf16(
    const int4* __restrict__ q, const int* __restrict__ zp,
    uint4* __restrict__ o, int n8) {
  int i = blockIdx.x * 256 + threadIdx.x;
  if (i >= n8) return;
  int z = zp[0];
  int4 a = q[2 * i];
  int4 b = q[2 * i + 1];
  union { __bf16 h[8]; uint4 u; } r;
  r.h[0] = (__bf16)(float)(a.x - z); r.h[1] = (__bf16)(float)(a.y - z);
  r.h[2] = (__bf16)(float)(a.z - z); r.h[3] = (__bf16)(float)(a.w - z);
  r.h[4] = (__bf16)(float)(b.x - z); r.h[5] = (__bf16)(float)(b.y - z);
  r.h[6] = (__bf16)(float)(b.z - z); r.h[7] = (__bf16)(float)(b.w - z);
  o[i] = r.u;
}

// ---------------- 256^2 GEMM, 2 phases / K-tile ----------------
// LDS half-slot (128 rows x 64 bf16 = 16KB), 16x32-subtiled + XOR swizzle;
// global_load_lds writes linear, source pre-swizzled, ds_read swizzled
// (both-sides involution, rule #21).
//
// Per tile t (d = t&1, e = d^1):
//  ph1: read af<-A(d,0), bf0<-B(d,0), bf1<-B(d,1) | stage Ab(t+1)
//       | MFMA Q(0,0), Q(0,1) | vmcnt(8) [Ab(t) ready] | barrier
//  ph2: read af<-A(d,1) | stage At,Bt,Bb(t+2)
//       | MFMA Q(1,1), Q(1,0) | vmcnt(8) [{At,Bt,Bb}(t+1) ready] | barrier
// Stage safety: Ab slot's last reader = ph2(t-1) (b2 intervenes);
// At/Bt/Bb slots' last readers = ph1(t) (b1 intervenes).
// vmcnt ledger (steady state, per-wave queue): entering ph1(t) =
// [Ab(t):2, {At,Bt,Bb}(t+1):6]; +2 in ph1 -> vmcnt(8) completes Ab(t);
// +6 in ph2 -> vmcnt(8) completes {At,Bt,Bb}(t+1).

#define SLOT_A(d, h) ((((d) * 2 + (h)) << 14))
#define SLOT_B(d, h) ((1 << 16) + (((d) * 2 + (h)) << 14))

#define STAGE(gbase, ldsOff, h, s)                                            \
  do {                                                                        \
    const char* g_ = (gbase) + (size_t)(h) * 128 * K2 + (size_t)(s) * 128;    \
    __builtin_amdgcn_global_load_lds(                                         \
        (const __attribute__((address_space(1))) void*)(g_),                  \
        (__attribute__((address_space(3))) void*)(smem + (ldsOff) + wave * 2048), \
        16, 0, 0);                                                            \
    __builtin_amdgcn_global_load_lds(                                         \
        (const __attribute__((address_space(1))) void*)(g_ + 64),             \
        (__attribute__((address_space(3))) void*)(smem + (ldsOff) + wave * 2048 + 1024), \
        16, 0, 0);                                                            \
  } while (0)

#define LOAD_AF(d, qm)                                                        \
  do {                                                                        \
    _Pragma("unroll") for (int mf = 0; mf < 4; ++mf)                          \
    _Pragma("unroll") for (int kh = 0; kh < 2; ++kh)                          \
        af[mf][kh] = *(const bf16x8*)(smem + SLOT_A(d, qm) +                  \
            (((wr * 4 + mf) * 2 + kh) << 10) + innerOff);                     \
  } while (0)

#define LOAD_BF(dst, d, qn)                                                   \
  do {                                                                        \
    _Pragma("unroll") for (int nf = 0; nf < 2; ++nf)                          \
    _Pragma("unroll") for (int kh = 0; kh < 2; ++kh)                          \
        dst[nf][kh] = *(const bf16x8*)(smem + SLOT_B(d, qn) +                 \
            (((wc * 2 + nf) * 2 + kh) << 10) + innerOff);                     \
  } while (0)

// kh outermost: 8 independent MFMAs before any same-accumulator reuse.
#define MFMA_QUAD(qm, qn, BFR)                                                \
  do {                                                                        \
    __builtin_amdgcn_s_setprio(1);                                            \
    _Pragma("unroll") for (int kh = 0; kh < 2; ++kh)                          \
    _Pragma("unroll") for (int mf = 0; mf < 4; ++mf)                          \
    _Pragma("unroll") for (int nf = 0; nf < 2; ++nf)                          \
        acc[qm][qn][mf][nf] = __builtin_amdgcn_mfma_f32_16x16x32_bf16(        \
            af[mf][kh], BFR[nf][kh], acc[qm][qn][mf][nf], 0, 0, 0);           \
    __builtin_amdgcn_s_setprio(0);                                            \
  } while (0)

// FULL: t+2 < nt (ph2 stages + vmcnt(8)); PRE: t+1 < nt (ph1 stage).
#define TILE2(t, d, e, FULL, PRE)                                             \
  do {                                                                        \
    /* ph1: Q(0,0) + Q(0,1) */                                                \
    LOAD_AF(d, 0);                                                            \
    LOAD_BF(bf0, d, 0);                                                       \
    if (PRE) STAGE(Abase, SLOT_A(e, 1), 1, (t) + 1);                          \
    LOAD_BF(bf1, d, 1);                                                       \
    MFMA_QUAD(0, 0, bf0);                                                     \
    MFMA_QUAD(0, 1, bf1);                                                     \
    asm volatile("s_waitcnt vmcnt(8)");                                       \
    __builtin_amdgcn_s_barrier();                                             \
    /* ph2: Q(1,1) + Q(1,0) */                                                \
    LOAD_AF(d, 1);                                                            \
    if (FULL) { STAGE(Abase, SLOT_A(d, 0), 0, (t) + 2);                       \
                STAGE(Bbase, SLOT_B(d, 0), 0, (t) + 2);                       \
                STAGE(Bbase, SLOT_B(d, 1), 1, (t) + 2); }                     \
    MFMA_QUAD(1, 1, bf1);                                                     \
    MFMA_QUAD(1, 0, bf0);                                                     \
    if (FULL) { asm volatile("s_waitcnt vmcnt(8)"); }                         \
    else      { asm volatile("s_waitcnt vmcnt(0)"); }                         \
    __builtin_amdgcn_s_barrier();                                             \
  } while (0)

__global__ __launch_bounds__(512, 2) void gemm256(
    const __bf16* __restrict__ A, const __bf16* __restrict__ Bw,
    const float* __restrict__ scale, const float* __restrict__ bias,
    float* __restrict__ C) {
  extern __shared__ char smem[];

  constexpr int N = 4096, K = 4096;
  constexpr size_t K2 = (size_t)K * 2;  // row stride in bytes

  const int tid  = threadIdx.x;
  const int wave = tid >> 6;
  const int lane = tid & 63;
  const int fr   = lane & 15;   // fragment row (A) / col (B,C)
  const int quad = lane >> 4;   // 0..3
  const int wr   = wave >> 2;   // 0..1 (M within quadrant)
  const int wc   = wave & 3;    // 0..3 (N within quadrant)

  // T1: XCD swizzle, nwg = 512 (divisible by 8).
  const int nwg = gridDim.x;
  const int cpx = nwg >> 3;
  const int swzid = ((int)blockIdx.x & 7) * cpx + ((int)blockIdx.x >> 3);
  const int nbx = N >> 8;          // 16
  const int bx = swzid % nbx;
  const int by = swzid / nbx;

  // staging per-lane source: row = wave*16 + lane>>2 within half,
  // col-byte = ((lane&3)<<4) ^ (((lane>>3)&3)<<4)  (inverse swizzle)
  const int rowLane = wave * 16 + (lane >> 2);
  const int colLane = ((lane & 3) << 4) ^ (((lane >> 3) & 3) << 4);
  const char* Abase = (const char*)A  + (size_t)(by * 256 + rowLane) * K2 + colLane;
  const char* Bbase = (const char*)Bw + (size_t)(bx * 256 + rowLane) * K2 + colLane;

  // ds_read per-lane inner offset (within 1KB subtile), swizzled:
  const int innerOff = (fr << 6) | ((quad << 4) ^ (((fr >> 1) & 3) << 4));

  f32x4 acc[2][2][4][2] = {};
  bf16x8 af[4][2], bf0[2][2], bf1[2][2];

  const int nt = K >> 6;  // 64 K-tiles
  (void)nt;

  // prologue (order = vmcnt ledger): tile0 {At,Bt,Bb}, Ab(0), tile1 {At,Bt,Bb}.
  STAGE(Abase, SLOT_A(0, 0), 0, 0);  // At(0)
  STAGE(Bbase, SLOT_B(0, 0), 0, 0);  // Bt(0)
  STAGE(Bbase, SLOT_B(0, 1), 1, 0);  // Bb(0)
  STAGE(Abase, SLOT_A(0, 1), 1, 0);  // Ab(0)
  STAGE(Abase, SLOT_A(1, 0), 0, 1);  // At(1)
  STAGE(Bbase, SLOT_B(1, 0), 0, 1);  // Bt(1)
  STAGE(Bbase, SLOT_B(1, 1), 1, 1);  // Bb(1)
  asm volatile("s_waitcnt vmcnt(8)");   // oldest 6 = {At,Bt,Bb}(0) complete
  __builtin_amdgcn_s_barrier();

  for (int tt = 0; tt < 62; tt += 2) {
    TILE2(tt,     0, 1, 1, 1);
    TILE2(tt + 1, 1, 0, 1, 1);
  }
  TILE2(62, 0, 1, 0, 1);
  TILE2(63, 1, 0, 0, 0);

  // epilogue: C/D layout col = lane&15, row = quad*4 + reg (m89-verified)
  const float s = scale[0];
#pragma unroll
  for (int qm = 0; qm < 2; ++qm)
#pragma unroll
    for (int mf = 0; mf < 4; ++mf) {
      const int row0 = by * 256 + qm * 128 + wr * 64 + mf * 16 + quad * 4;
#pragma unroll
      for (int qn = 0; qn < 2; ++qn)
#pragma unroll
        for (int nf = 0; nf < 2; ++nf) {
          const int col = bx * 256 + qn * 128 + wc * 32 + nf * 16 + fr;
          const float bv = bias[col];
          float* cp = C + (size_t)row0 * N + col;
#pragma unroll
          for (int r = 0; r < 4; ++r)
            cp[(size_t)r * N] = s * acc[qm][qn][mf][nf][r] + bv;
        }
    }
}

// ---------------- launch ----------------

extern "C" void kernel_launch(void* const* d_in, const int* in_sizes, int n_in,
                              void* d_out, int out_size, void* d_ws, size_t ws_size,
                              hipStream_t stream) {
  const int M = 8192, N = 4096, K = 4096;

  const float* x    = (const float*)d_in[0];
  const int*   qw   = (const int*)d_in[1];
  const int*   zp   = (const int*)d_in[2];
  const float* sc   = (const float*)d_in[3];
  const float* bias = (const float*)d_in[4];
  float* out = (float*)d_out;

  __bf16* x_bf = (__bf16*)d_ws;
  __bf16* w_bf = (__bf16*)((char*)d_ws + (size_t)M * K * sizeof(__bf16));

  {
    int n8 = (M * K) / 8;
    cvt_x_bf16<<<n8 / 256, 256, 0, stream>>>((const float4*)x, (uint4*)x_bf, n8);
  }
  {
    int n8 = (N * K) / 8;
    cvt_w_bf16<<<n8 / 256, 256, 0, stream>>>((const int4*)qw, zp, (uint4*)w_bf, n8);
  }

  static bool attr_set = false;
  if (!attr_set) {
    hipFuncSetAttribute((const void*)gemm256,
                        hipFuncAttributeMaxDynamicSharedMemorySize, 131072);
    attr_set = true;
  }
  gemm256<<<dim3(512), dim3(512), 131072, stream>>>(x_bf, w_bf, sc, bias, out);
}